// Round 2
// baseline (315.569 us; speedup 1.0000x reference)
//
#include <hip/hip_runtime.h>
#include <hip/hip_bf16.h>

typedef unsigned int u32;

// Problem constants (from reference): FACTOR=2, DIM=3, B=2, S=128, MAXS=64, C=32
// code = b*2^18 + (x>>1)*2^12 + (y>>1)*2^6 + (z>>1), code in [0, 524288)
static constexpr u32 NCODES = 524288u;   // B * MAXS^3 = 2 * 64^3
// scan geometry: 512 blocks x 1024 codes (256 threads x uint4)

__device__ __forceinline__ u32 code_of(int4 c) {
  return ((u32)c.x << 18) + ((u32)(c.y >> 1) << 12) +
         ((u32)(c.z >> 1) << 6) + (u32)(c.w >> 1);
}

// 1) mark[code] = 1 for every voxel (idempotent plain stores, no atomics needed)
__global__ void k_mark(const int4* __restrict__ coords, u32* __restrict__ mark, int n) {
  int i = blockIdx.x * blockDim.x + threadIdx.x;
  if (i >= n) return;
  mark[code_of(coords[i])] = 1u;
}

// 2) per-1024-chunk sums of the mark array
__global__ void k_reduce(const u32* __restrict__ mark, u32* __restrict__ bsum) {
  int b = blockIdx.x, t = threadIdx.x;
  uint4 m = ((const uint4*)mark)[b * 256 + t];
  u32 s = m.x + m.y + m.z + m.w;
  for (int d = 32; d > 0; d >>= 1) s += __shfl_down(s, d, 64);
  __shared__ u32 ws4[4];
  if ((t & 63) == 0) ws4[t >> 6] = s;
  __syncthreads();
  if (t == 0) bsum[b] = ws4[0] + ws4[1] + ws4[2] + ws4[3];
}

// 3) exclusive scan of the 512 chunk sums (single block, Hillis-Steele)
__global__ void k_scan512(const u32* __restrict__ bsum, u32* __restrict__ boff) {
  __shared__ u32 s[512];
  int t = threadIdx.x;
  u32 v = bsum[t];
  s[t] = v;
  __syncthreads();
  for (int d = 1; d < 512; d <<= 1) {
    u32 add = (t >= d) ? s[t - d] : 0u;
    __syncthreads();
    s[t] += add;
    __syncthreads();
  }
  boff[t] = s[t] - v;  // exclusive
}

__device__ __forceinline__ void wrc(float* __restrict__ outc, u32 r, u32 code) {
  float4 p;
  p.x = (float)(code >> 18);         // batch
  p.y = (float)((code >> 12) & 63u);
  p.z = (float)((code >> 6) & 63u);
  p.w = (float)(code & 63u);
  ((float4*)outc)[r] = p;
}

// 4) per-chunk exclusive scan: marks -> ranks (in place), and scatter decoded
//    coords for marked codes at out[N*256 + rank*4]
__global__ void k_scan_scatter(u32* __restrict__ codes, const u32* __restrict__ boff,
                               float* __restrict__ outc) {
  int b = blockIdx.x, t = threadIdx.x;
  uint4 m = ((const uint4*)codes)[b * 256 + t];
  u32 tsum = m.x + m.y + m.z + m.w;
  u32 incl = tsum;
  int lane = t & 63;
  for (int d = 1; d < 64; d <<= 1) {
    u32 v = __shfl_up(incl, d, 64);
    if (lane >= d) incl += v;
  }
  __shared__ u32 wsum[4];
  if (lane == 63) wsum[t >> 6] = incl;
  __syncthreads();
  u32 woff = boff[b];
  for (int w = 0; w < (t >> 6); ++w) woff += wsum[w];
  u32 e0 = woff + incl - tsum;
  u32 e1 = e0 + m.x, e2 = e1 + m.y, e3 = e2 + m.z;
  ((uint4*)codes)[b * 256 + t] = make_uint4(e0, e1, e2, e3);  // ranks overwrite marks
  u32 base = (u32)b * 1024u + (u32)t * 4u;
  if (m.x) wrc(outc, e0, base + 0u);
  if (m.y) wrc(outc, e1, base + 1u);
  if (m.z) wrc(outc, e2, base + 2u);
  if (m.w) wrc(outc, e3, base + 3u);
}

// Pre-fill all N coord rows with the fill sentinel decode [2,0,0,0] (f32)
__global__ void k_fillc(float* __restrict__ outc, int n) {
  int i = blockIdx.x * blockDim.x + threadIdx.x;
  if (i >= n) return;
  ((float4*)outc)[i] = make_float4(2.0f, 0.0f, 0.0f, 0.0f);
}

// 5) scatter feats: thread = (voxel, quarter-row of 4 channels), exact f32 copy
__global__ void k_scatter(const float4* __restrict__ feats, const int4* __restrict__ coords,
                          const u32* __restrict__ rank, float* __restrict__ out, int n8) {
  int tid = blockIdx.x * blockDim.x + threadIdx.x;
  if (tid >= n8) return;
  int row = tid >> 3, q = tid & 7;
  int4 c = coords[row];
  u32 code = code_of(c);
  u32 sub = (u32)(c.y & 1) + ((u32)(c.z & 1) << 1) + ((u32)(c.w & 1) << 2);
  float4 f = feats[tid];
  ((float4*)out)[((size_t)rank[code] * 8u + sub) * 8u + (u32)q] = f;
}

extern "C" void kernel_launch(void* const* d_in, const int* in_sizes, int n_in,
                              void* d_out, int out_size, void* d_ws, size_t ws_size,
                              hipStream_t stream) {
  const float* feats = (const float*)d_in[0];
  const int* coords  = (const int*)d_in[1];
  int n = in_sizes[1] / 4;                 // N voxels (262144)
  float* out = (float*)d_out;              // f32 output: [N,256] feats ++ [N,4] coords
  size_t featsElems = (size_t)n * 256;
  float* outc = out + featsElems;

  u32* codes = (u32*)d_ws;                 // NCODES u32: marks, then ranks (in place)
  u32* bsum  = codes + NCODES;             // 512
  u32* boff  = bsum + 512;                 // 512

  hipMemsetAsync(d_out, 0, featsElems * sizeof(float), stream);  // zero feats region
  hipMemsetAsync(d_ws, 0, NCODES * sizeof(u32), stream);         // zero marks

  k_fillc<<<(n + 255) / 256, 256, 0, stream>>>(outc, n);
  k_mark<<<(n + 255) / 256, 256, 0, stream>>>((const int4*)coords, codes, n);
  k_reduce<<<NCODES / 1024, 256, 0, stream>>>(codes, bsum);
  k_scan512<<<1, 512, 0, stream>>>(bsum, boff);
  k_scan_scatter<<<NCODES / 1024, 256, 0, stream>>>(codes, boff, outc);
  k_scatter<<<(n * 8 + 255) / 256, 256, 0, stream>>>((const float4*)feats,
                                                     (const int4*)coords, codes, out, n * 8);
}